// Round 1
// baseline (481.458 us; speedup 1.0000x reference)
//
#include <hip/hip_runtime.h>
#include <stdint.h>

// Problem constants (match reference)
#define NP 32    // num networks (P)
#define NH 128   // hidden (H)
#define NB 32    // batch (B)
#define NT 256   // time (T)
#define FH 512   // 4*H

typedef __attribute__((ext_vector_type(4))) float float4_t;
typedef __attribute__((ext_vector_type(8))) __bf16 bf16x8;

static __device__ __forceinline__ float4_t mfma_bf16(bf16x8 a, bf16x8 b, float4_t c) {
  return __builtin_amdgcn_mfma_f32_16x16x32_bf16(a, b, c, 0, 0, 0);
}

#define LOG2E 1.4426950408889634f

// Grid: 64 blocks = 32 networks x 2 batch-halves (16 batches each).
// Block: 512 threads = 8 waves; wave w owns hidden units [16w, 16w+16),
// i.e. 4 MFMA N-tiles (cols g*128 + 16w + l16 for gate g in {i,f,g,o}).
// Weights: bf16 B-fragments in VGPRs (80 VGPR/lane), loaded once.
// K = 160 = [x:32][h:128] -> 5 K-chunks of 32 for mfma_f32_16x16x32_bf16.
// Gate scales folded into weights/biases: i,f,o cols scaled by -log2e
// (sigmoid = rcp(1+exp2(y))), g cols by -2log2e (tanh = (1-e)*rcp(1+e)).
__global__ __launch_bounds__(512, 2) void clstm_main(
    const float* __restrict__ X, const float* __restrict__ Wih,
    const float* __restrict__ Whh, const float* __restrict__ bih,
    const float* __restrict__ bhh, const float* __restrict__ Wout,
    const float* __restrict__ bout, float* __restrict__ out)
{
  const int net = blockIdx.x >> 1, bg = blockIdx.x & 1;
  const int tid = threadIdx.x;
  const int w = tid >> 6, lane = tid & 63;
  const int quad = lane >> 4, l16 = lane & 15;

  // h A-fragments, double buffered: [buf][kchunk][kquad][m][j] (16B rows -> ds_read_b128)
  __shared__ __bf16 hfrag[2][4][4][16][8];
  // per-wave output partials: [buf][wave][batch]
  __shared__ float opart[2][8][16];

  { // zero the t=0 input buffer (h0 = 0): 4KB = 1024 ints, 2 per thread
    int* hz = (int*)&hfrag[0][0][0][0][0];
    hz[2*tid] = 0; hz[2*tid+1] = 0;
  }
  __syncthreads();

  // ---- load weights into register B-fragments (one-time) ----
  // B-frag layout for 16x16x32: lane holds B[k = quad*8 + j][n = l16] (8 consecutive k).
  // W_ih is (P,4H,P) [net][col][d], W_hh is (P,4H,H) [net][col][h]: k contiguous. 
  bf16x8 bfrag[4][5];
  float bias[4];
#pragma unroll
  for (int g = 0; g < 4; ++g) {
    const float scale = (g == 2) ? (-2.0f*LOG2E) : (-LOG2E);
    const int col = g*NH + w*16 + l16;
#pragma unroll
    for (int kc = 0; kc < 5; ++kc) {
      const float* src = (kc == 0) ? (Wih + (net*FH + col)*NP + quad*8)
                                   : (Whh + (net*FH + col)*NH + (kc-1)*32 + quad*8);
      bf16x8 bf;
#pragma unroll
      for (int j = 0; j < 8; ++j) bf[j] = (__bf16)(src[j] * scale);
      bfrag[g][kc] = bf;
    }
    bias[g] = (bih[net*FH + col] + bhh[net*FH + col]) * scale;
  }
  const float woj = Wout[net*NH + w*16 + l16];  // W_out for this lane's unit
  const float bo  = bout[net];

  float4_t c4 = {0.f, 0.f, 0.f, 0.f};  // c state: this lane's unit, 4 batches (rows quad*4+r)

  // x A-frag source: lane reads X[bg*16+l16][t][quad*8 .. +8]
  const float* xrow = X + (size_t)(bg*16 + l16)*(NT*NP) + quad*8;

  // where this lane's h values land in the next-step A-frag layout
  const int hj = w*16 + l16;                       // hidden unit index 0..127
  const int kcp = hj >> 5, q2 = (hj >> 3) & 3, jj = hj & 7;

  for (int t = 0; t < NT; ++t) {
    const int rd = t & 1, wr = rd ^ 1;

    // ---- A fragments ----
    bf16x8 ax;
    {
      const float* xp = xrow + t*NP;
      float xv[8];
      *(float4_t*)&xv[0] = *(const float4_t*)xp;
      *(float4_t*)&xv[4] = *(const float4_t*)(xp + 4);
#pragma unroll
      for (int j = 0; j < 8; ++j) ax[j] = (__bf16)xv[j];
    }
    bf16x8 ah[4];
#pragma unroll
    for (int kc = 0; kc < 4; ++kc)
      ah[kc] = *(const bf16x8*)&hfrag[rd][kc][quad][l16][0];

    // ---- MFMA: acc[g] = bias + [x,h] @ Wcat (scaled) ----
    float4_t acc[4];
#pragma unroll
    for (int g = 0; g < 4; ++g) {
      float4_t a = {bias[g], bias[g], bias[g], bias[g]};
      a = mfma_bf16(ax, bfrag[g][0], a);
#pragma unroll
      for (int kc = 0; kc < 4; ++kc) a = mfma_bf16(ah[kc], bfrag[g][kc+1], a);
      acc[g] = a;
    }

    // ---- activations + state update (fp32) ----
    // acc rows: batch m = quad*4 + r; col: this lane's unit.
    float4_t h4, po;
#pragma unroll
    for (int r = 0; r < 4; ++r) {
      float ei = __builtin_amdgcn_exp2f(acc[0][r]);           // exp(-i_pre)
      float ig = __builtin_amdgcn_rcpf(1.0f + ei);            // sigmoid
      float ef = __builtin_amdgcn_exp2f(acc[1][r]);
      float fg = __builtin_amdgcn_rcpf(1.0f + ef);
      float eg = __builtin_amdgcn_exp2f(fminf(acc[2][r], 126.0f)); // exp(-2 g_pre)
      float rg = __builtin_amdgcn_rcpf(1.0f + eg);
      float gg = (1.0f - eg) * rg;                            // tanh
      float eo = __builtin_amdgcn_exp2f(acc[3][r]);
      float og = __builtin_amdgcn_rcpf(1.0f + eo);
      float c  = fg * c4[r] + ig * gg;
      c4[r] = c;
      float ec = __builtin_amdgcn_exp2f(fminf(c * (-2.0f*LOG2E), 126.0f));
      float rc = __builtin_amdgcn_rcpf(1.0f + ec);
      float th = (1.0f - ec) * rc;                            // tanh(c)
      float h  = og * th;
      h4[r] = h;
      po[r] = h * woj;                                        // head partial
    }

    // ---- write h (bf16) into next step's A-frag buffer ----
#pragma unroll
    for (int r = 0; r < 4; ++r)
      hfrag[wr][kcp][q2][quad*4 + r][jj] = (__bf16)h4[r];

    // ---- reduce head partial over the 16 unit-lanes of this wave ----
#pragma unroll
    for (int m = 1; m < 16; m <<= 1) {
#pragma unroll
      for (int r = 0; r < 4; ++r) po[r] += __shfl_xor(po[r], m, 64);
    }
    if (l16 == 0) *(float4_t*)&opart[rd][w][quad*4] = po;     // batches quad*4..+3

    __syncthreads();

    // ---- finalize pred[b][t][net] for this step (cross-wave sum of 8 partials) ----
    if (lane < 16) {
      const int w8 = lane & 7, bl = 2*w + (lane >> 3);        // wave handles 2 batches
      float v = opart[rd][w8][bl];
      v += __shfl_xor(v, 1, 64);
      v += __shfl_xor(v, 2, 64);
      v += __shfl_xor(v, 4, 64);
      if (w8 == 0) out[(size_t)(bg*16 + bl)*(NT*NP) + t*NP + net] = v + bo;
    }
  }
}

extern "C" void kernel_launch(void* const* d_in, const int* in_sizes, int n_in,
                              void* d_out, int out_size, void* d_ws, size_t ws_size,
                              hipStream_t stream) {
  const float* X    = (const float*)d_in[0];
  const float* Wih  = (const float*)d_in[1];
  const float* Whh  = (const float*)d_in[2];
  const float* bih  = (const float*)d_in[3];
  const float* bhh  = (const float*)d_in[4];
  const float* Wout = (const float*)d_in[5];
  const float* bout = (const float*)d_in[6];
  float* out = (float*)d_out;
  (void)d_ws; (void)ws_size; (void)in_sizes; (void)n_in; (void)out_size;

  clstm_main<<<64, 512, 0, stream>>>(X, Wih, Whh, bih, bhh, Wout, bout, out);
}

// Round 2
// 318.134 us; speedup vs baseline: 1.5134x; 1.5134x over previous
//
#include <hip/hip_runtime.h>
#include <stdint.h>

// Problem constants (match reference)
#define NP 32    // num networks (P)
#define NH 128   // hidden (H)
#define NB 32    // batch (B)
#define NT 256   // time (T)
#define FH 512   // 4*H

typedef __attribute__((ext_vector_type(4))) float float4_t;
typedef __attribute__((ext_vector_type(8))) __bf16 bf16x8;

static __device__ __forceinline__ float4_t mfma_bf16(bf16x8 a, bf16x8 b, float4_t c) {
  return __builtin_amdgcn_mfma_f32_16x16x32_bf16(a, b, c, 0, 0, 0);
}

#define LOG2E 1.4426950408889634f

// Raw workgroup barrier: drains LDS ops only (cross-wave h visibility), does
// NOT drain vmcnt — pending global loads/stores stay in flight across it.
// __syncthreads() would emit s_waitcnt vmcnt(0) and stall ~300+ cyc/step.
#define BAR() __asm__ volatile("s_waitcnt lgkmcnt(0)\n\ts_barrier" ::: "memory")

// Grid: 64 blocks = 32 networks x 2 batch-halves (16 batches each).
// Block: 512 threads = 8 waves; wave w owns hidden units [16w, 16w+16).
// Weights live in VGPRs as bf16 B-fragments (80 VGPR/lane), loaded once.
// Gate scales folded into weights/biases: i,f,o cols scaled by -log2e
// (sigmoid = rcp(1+exp2(y))), g cols by -2log2e (tanh = (1-e)*rcp(1+e)).
// STORE_HS=1: write h_t (bf16) to hs[] fire-and-forget; head in 2nd kernel.
// STORE_HS=0: fallback in-loop head (if ws_size too small).
template<int STORE_HS>
__global__ __launch_bounds__(512, 2) void clstm_main(
    const float* __restrict__ X, const float* __restrict__ Wih,
    const float* __restrict__ Whh, const float* __restrict__ bih,
    const float* __restrict__ bhh, const float* __restrict__ Wout,
    const float* __restrict__ bout, float* __restrict__ out,
    __bf16* __restrict__ hs)
{
  const int net = blockIdx.x >> 1, bg = blockIdx.x & 1;
  const int tid = threadIdx.x;
  const int w = tid >> 6, lane = tid & 63;
  const int quad = lane >> 4, l16 = lane & 15;

  // h A-fragments, double buffered: [buf][kchunk][kquad][m][j] (16B rows -> ds_read_b128)
  __shared__ __bf16 hfrag[2][4][4][16][8];
  // per-wave output partials (fallback path only): [buf][wave][batch]
  __shared__ float opart[2][8][16];

  { // zero the t=0 input buffer (h0 = 0): 4KB = 1024 ints, 2 per thread
    int* hz = (int*)&hfrag[0][0][0][0][0];
    hz[2*tid] = 0; hz[2*tid+1] = 0;
  }
  __syncthreads();  // once, outside the loop — full drain is fine here

  // ---- load weights into register B-fragments (one-time) ----
  // B-frag layout for 16x16x32: lane holds B[k = quad*8 + j][n = l16].
  bf16x8 bfrag[4][5];
  float bias[4];
#pragma unroll
  for (int g = 0; g < 4; ++g) {
    const float scale = (g == 2) ? (-2.0f*LOG2E) : (-LOG2E);
    const int col = g*NH + w*16 + l16;
#pragma unroll
    for (int kc = 0; kc < 5; ++kc) {
      const float* src = (kc == 0) ? (Wih + (net*FH + col)*NP + quad*8)
                                   : (Whh + (net*FH + col)*NH + (kc-1)*32 + quad*8);
      bf16x8 bf;
#pragma unroll
      for (int j = 0; j < 8; ++j) bf[j] = (__bf16)(src[j] * scale);
      bfrag[g][kc] = bf;
    }
    bias[g] = (bih[net*FH + col] + bhh[net*FH + col]) * scale;
  }
  const float woj = Wout[net*NH + w*16 + l16];  // fallback head weight
  const float bo  = bout[net];

  float4_t c4 = {0.f, 0.f, 0.f, 0.f};  // c state: lane's unit, batches quad*4+r

  // x A-frag source: lane reads X[bg*16+l16][t][quad*8 .. +8]
  const float* xrow = X + (size_t)(bg*16 + l16)*(NT*NP) + quad*8;

  // where this lane's h values land in the next-step A-frag layout
  const int hj = w*16 + l16;                       // hidden unit index 0..127
  const int kcp = hj >> 5, q2 = (hj >> 3) & 3, jj = hj & 7;

  // hs store base: hs[((t*NP + net)*NB + b)*NH + hj], b = bg*16 + quad*4 + r
  __bf16* hsp = STORE_HS ? (hs + ((size_t)net*NB + bg*16 + quad*4)*NH + hj) : nullptr;

  // preload + convert x for t=0
  bf16x8 ax;
  {
    float xv[8];
    *(float4_t*)&xv[0] = *(const float4_t*)xrow;
    *(float4_t*)&xv[4] = *(const float4_t*)(xrow + 4);
#pragma unroll
    for (int j = 0; j < 8; ++j) ax[j] = (__bf16)xv[j];
  }

  for (int t = 0; t < NT; ++t) {
    const int rd = t & 1, wr = rd ^ 1;

    // ---- 1. h A-frags: issue LDS reads first (latency ~120 cyc) ----
    bf16x8 ah[4];
#pragma unroll
    for (int kc = 0; kc < 4; ++kc)
      ah[kc] = *(const bf16x8*)&hfrag[rd][kc][quad][l16][0];

    // ---- 2. prefetch x for t+1 (overlaps LDS latency) ----
    float xv[8];
    {
      const int tn = (t + 1 < NT) ? t + 1 : t;
      const float* xp = xrow + tn*NP;
      *(float4_t*)&xv[0] = *(const float4_t*)xp;
      *(float4_t*)&xv[4] = *(const float4_t*)(xp + 4);
    }

    // ---- 3. x-projection MFMAs (independent of h, overlap LDS latency) ----
    float4_t acc[4];
#pragma unroll
    for (int g = 0; g < 4; ++g) {
      float4_t a = {bias[g], bias[g], bias[g], bias[g]};
      acc[g] = mfma_bf16(ax, bfrag[g][0], a);
    }

    // ---- 4. recurrent MFMAs ----
#pragma unroll
    for (int g = 0; g < 4; ++g) {
      float4_t a = acc[g];
#pragma unroll
      for (int kc = 0; kc < 4; ++kc) a = mfma_bf16(ah[kc], bfrag[g][kc+1], a);
      acc[g] = a;
    }

    // ---- 5. activations + state update (fp32) ----
    float4_t h4, po;
#pragma unroll
    for (int r = 0; r < 4; ++r) {
      float ei = __builtin_amdgcn_exp2f(acc[0][r]);           // exp(-i_pre)
      float ig = __builtin_amdgcn_rcpf(1.0f + ei);            // sigmoid
      float ef = __builtin_amdgcn_exp2f(acc[1][r]);
      float fg = __builtin_amdgcn_rcpf(1.0f + ef);
      float eg = __builtin_amdgcn_exp2f(fminf(acc[2][r], 126.0f)); // exp(-2 g_pre)
      float rg = __builtin_amdgcn_rcpf(1.0f + eg);
      float gg = (1.0f - eg) * rg;                            // tanh
      float eo = __builtin_amdgcn_exp2f(acc[3][r]);
      float og = __builtin_amdgcn_rcpf(1.0f + eo);
      float c  = fg * c4[r] + ig * gg;
      c4[r] = c;
      float ec = __builtin_amdgcn_exp2f(fminf(c * (-2.0f*LOG2E), 126.0f));
      float rc = __builtin_amdgcn_rcpf(1.0f + ec);
      float th = (1.0f - ec) * rc;                            // tanh(c)
      float h  = og * th;
      h4[r] = h;
      if (!STORE_HS) po[r] = h * woj;
    }

    // ---- 6. write h' (bf16) to next-step A-frag buffer + hs (fire&forget) ----
#pragma unroll
    for (int r = 0; r < 4; ++r) {
      __bf16 hb = (__bf16)h4[r];
      hfrag[wr][kcp][q2][quad*4 + r][jj] = hb;
      if (STORE_HS) hsp[((size_t)t*NP*NB + r)*NH] = hb;
    }

    // ---- 7. convert next x (off critical path) ----
#pragma unroll
    for (int j = 0; j < 8; ++j) ax[j] = (__bf16)xv[j];

    if (!STORE_HS) {
      // fallback in-loop head: wave reduce + cross-wave via opart
#pragma unroll
      for (int m = 1; m < 16; m <<= 1) {
#pragma unroll
        for (int r = 0; r < 4; ++r) po[r] += __shfl_xor(po[r], m, 64);
      }
      if (l16 == 0) *(float4_t*)&opart[rd][w][quad*4] = po;
    }

    BAR();  // lgkmcnt-only barrier

    if (!STORE_HS) {
      if (lane < 16) {
        const int w8 = lane & 7, bl = 2*w + (lane >> 3);
        float v = opart[rd][w8][bl];
        v += __shfl_xor(v, 1, 64);
        v += __shfl_xor(v, 2, 64);
        v += __shfl_xor(v, 4, 64);
        if (w8 == 0) out[(size_t)(bg*16 + bl)*(NT*NP) + t*NP + net] = v + bo;
      }
    }
  }
}

// Head: out[b][t][n] = sum_h hs[t][n][b][h] * Wout[n][h] + bout[n]
// One wave per (t,net): lane = (h-half, b); 64 bf16 loads/lane + 1 shuffle.
__global__ __launch_bounds__(256, 4) void clstm_head(
    const __bf16* __restrict__ hs, const float* __restrict__ Wout,
    const float* __restrict__ bout, float* __restrict__ out)
{
  const int w = threadIdx.x >> 6, lane = threadIdx.x & 63;
  const int gw = blockIdx.x * 4 + w;          // 0..8191
  const int t = gw >> 5, net = gw & 31;
  const int b = lane & 31, hh = (lane >> 5) * 64;
  const __bf16* hp = hs + (((size_t)t*NP + net)*NB + b)*NH + hh;
  const float* wp = Wout + net*NH + hh;
  float acc = 0.f;
#pragma unroll
  for (int j = 0; j < 64; j += 8) {
    bf16x8 hv = *(const bf16x8*)(hp + j);
    float4_t w0 = *(const float4_t*)(wp + j);
    float4_t w1 = *(const float4_t*)(wp + j + 4);
    acc += (float)hv[0]*w0[0] + (float)hv[1]*w0[1] +
           (float)hv[2]*w0[2] + (float)hv[3]*w0[3] +
           (float)hv[4]*w1[0] + (float)hv[5]*w1[1] +
           (float)hv[6]*w1[2] + (float)hv[7]*w1[3];
  }
  acc += __shfl_xor(acc, 32, 64);
  if (lane < 32)
    out[((size_t)b*NT + t)*NP + net] = acc + bout[net];
}

extern "C" void kernel_launch(void* const* d_in, const int* in_sizes, int n_in,
                              void* d_out, int out_size, void* d_ws, size_t ws_size,
                              hipStream_t stream) {
  const float* X    = (const float*)d_in[0];
  const float* Wih  = (const float*)d_in[1];
  const float* Whh  = (const float*)d_in[2];
  const float* bih  = (const float*)d_in[3];
  const float* bhh  = (const float*)d_in[4];
  const float* Wout = (const float*)d_in[5];
  const float* bout = (const float*)d_in[6];
  float* out = (float*)d_out;
  (void)in_sizes; (void)n_in; (void)out_size;

  const size_t hs_bytes = (size_t)NT * NP * NB * NH * sizeof(__bf16); // 64 MB
  if (ws_size >= hs_bytes) {
    __bf16* hs = (__bf16*)d_ws;
    clstm_main<1><<<64, 512, 0, stream>>>(X, Wih, Whh, bih, bhh, Wout, bout, out, hs);
    clstm_head<<<2048, 256, 0, stream>>>(hs, Wout, bout, out);
  } else {
    clstm_main<0><<<64, 512, 0, stream>>>(X, Wih, Whh, bih, bhh, Wout, bout, out, nullptr);
  }
}